// Round 7
// baseline (196.608 us; speedup 1.0000x reference)
//
#include <hip/hip_runtime.h>

#define BB 64
#define CC 512
#define NPIX 784
#define KK 32
#define NSA 13          // kA: 13 splits of 64 px (split 12 overlaps: p0=720)
#define AS 800          // A row stride in shorts (784 padded to 25*32)
#define RS 66           // kA LDS x-tile row stride (dwords): <=2-way bank aliasing
#define NSTEP 24        // kB full 32-wide n-steps (24*32 = 768), +1 predicated tail

typedef __attribute__((ext_vector_type(8))) short short8;
typedef __attribute__((ext_vector_type(4))) float floatx4;

// workspace layout: A bf16 [64][32][800] (3.28 MB), then wsum_p fp32 [13][64][32]
#define WSUM_OFF (BB * KK * AS)   // in shorts; byte offset 6553600 (16-aligned)

__device__ __forceinline__ unsigned short f2bf(float f) {
    union { float f; unsigned u; } v; v.f = f;
    return (unsigned short)((v.u + 0x7FFFu + ((v.u >> 16) & 1u)) >> 16);
}
__device__ __forceinline__ short8 pack8(const float4& a, const float4& b) {
    short8 r;
    r[0] = (short)f2bf(a.x); r[1] = (short)f2bf(a.y);
    r[2] = (short)f2bf(a.z); r[3] = (short)f2bf(a.w);
    r[4] = (short)f2bf(b.x); r[5] = (short)f2bf(b.y);
    r[6] = (short)f2bf(b.z); r[7] = (short)f2bf(b.w);
    return r;
}

// issue chunk (chk): 4 coalesced float4 loads per thread (rows r0+16j, px p4*4)
#define ISSUE(chk, P0, P1, P2, P3) {                                           \
    const float* _s = xb + (size_t)(chk) * 64 * NPIX + p4 * 4;                 \
    P0 = *(const float4*)&_s[(size_t)(r0     ) * NPIX];                        \
    P1 = *(const float4*)&_s[(size_t)(r0 + 16) * NPIX];                        \
    P2 = *(const float4*)&_s[(size_t)(r0 + 32) * NPIX];                        \
    P3 = *(const float4*)&_s[(size_t)(r0 + 48) * NPIX]; }

// commit to LDS buffer bf: float2 pairs (RS=66 keeps odd rows 8B-aligned only)
#define COMMIT1(bf, RR, P) {                                                   \
    float* _d = &xt[bf][(RR) * RS + p4 * 4];                                   \
    *(float2*)&_d[0] = make_float2(P.x, P.y);                                  \
    *(float2*)&_d[2] = make_float2(P.z, P.w); }
#define COMMIT(bf, P0, P1, P2, P3) {                                           \
    COMMIT1(bf, r0,      P0); COMMIT1(bf, r0 + 16, P1);                        \
    COMMIT1(bf, r0 + 32, P2); COMMIT1(bf, r0 + 48, P3); }

// ---------------------------------------------------------------------------
// kA: per (64-px split, batch): A[k][px] = softmax_k(scale_k*(xsq+csq_k-2 x.c_k))
//  - x staged COALESCED (float4 across px) into transposed LDS tile [64c][64px],
//    double-buffered, with a 3-chunk-deep register pipeline (issue ch+3 /
//    commit ch+1 / compute ch) -> ~2 iterations (~600cy) of load lead time.
//  - raw s_barrier + lgkmcnt(0) only: global loads stay in flight across
//    barriers (no vmcnt(0) drain -- the round-4 killer).
//  - MFMA A-frag: 8x ds_read_b32 stride RS=66 (<=2-way conflict = free).
//  - cw fragments + csq direct from global (L1/L2-hot). LDS ~35 KB.
// ---------------------------------------------------------------------------
__global__ __launch_bounds__(256, 4) void kA(const float* __restrict__ x,
                                             const float* __restrict__ cw,
                                             const float* __restrict__ scale,
                                             unsigned short* __restrict__ Ag)
{
    __shared__ __align__(16) float xt[2][64 * RS];   // 33792 B
    __shared__ float csq_p[8][KK];
    __shared__ float csq_l[KK];
    __shared__ float wredA[4][KK];

    const int t    = threadIdx.x;
    const int lane = t & 63, w = t >> 6;
    const int col  = lane & 15, quad = lane >> 4;
    const int split = blockIdx.x, b = blockIdx.y;
    const int p0    = (split < 12) ? split * 64 : 720;   // split 12 overlaps by 48 px

    // ---- zero A pad region n in [784,800) once per batch (idempotent) ----
    if (split == 0 && t < 64) {
        const short8 z = {0, 0, 0, 0, 0, 0, 0, 0};
        const int k = t >> 1, off = (t & 1) * 8;
        *(short8*)&Ag[(size_t)b * KK * AS + (size_t)k * AS + NPIX + off] = z;
    }

    // ---- csq partials direct from global cw (fp32) ----
    {
        const int k = t & 31, part = t >> 5;
        const float* cp = cw + k * CC + part * 64;
        float s = 0.f;
#pragma unroll
        for (int i = 0; i < 16; ++i) {
            const float4 v = *(const float4*)&cp[i * 4];
            s += v.x * v.x + v.y * v.y + v.z * v.z + v.w * v.w;
        }
        csq_p[part][k] = s;
    }
    __syncthreads();
    if (t < KK) {
        float s = 0.f;
#pragma unroll
        for (int p = 0; p < 8; ++p) s += csq_p[p][t];
        csq_l[t] = s;
    }

    const float* xb = x + (size_t)b * CC * NPIX + p0;
    const int r0 = t >> 4, p4 = t & 15;      // staging: c-row base / px-float4
    const int wcol = w * 16 + col;           // this wave's px column in LDS tile

    // ---- prologue: fill 3-deep pipeline, commit chunk 0 ----
    float4 pA0, pA1, pA2, pA3, pB0, pB1, pB2, pB3, pC0, pC1, pC2, pC3;
    ISSUE(0, pA0, pA1, pA2, pA3);
    ISSUE(1, pB0, pB1, pB2, pB3);
    ISSUE(2, pC0, pC1, pC2, pC3);
    COMMIT(0, pA0, pA1, pA2, pA3);           // counted vmcnt wait on pA only
    asm volatile("s_waitcnt lgkmcnt(0)" ::: "memory");
    __builtin_amdgcn_s_barrier();
    asm volatile("" ::: "memory");

    floatx4 acc0 = {0.f, 0.f, 0.f, 0.f};
    floatx4 acc1 = {0.f, 0.f, 0.f, 0.f};
    float xsqp = 0.f;

#pragma unroll
    for (int ch = 0; ch < 8; ++ch) {
        // issue chunk ch+3 into the slot freed by chunk ch (committed last iter)
        if (ch + 3 < 8) {
            if (ch % 3 == 0)      { ISSUE(ch + 3, pA0, pA1, pA2, pA3); }
            else if (ch % 3 == 1) { ISSUE(ch + 3, pB0, pB1, pB2, pB3); }
            else                  { ISSUE(ch + 3, pC0, pC1, pC2, pC3); }
        }
        // commit chunk ch+1 (issued 2 iterations ago -> loads long complete)
        if (ch + 1 < 8) {
            const int nb = (ch + 1) & 1;
            if ((ch + 1) % 3 == 0)      { COMMIT(nb, pA0, pA1, pA2, pA3); }
            else if ((ch + 1) % 3 == 1) { COMMIT(nb, pB0, pB1, pB2, pB3); }
            else                        { COMMIT(nb, pC0, pC1, pC2, pC3); }
        }
        // compute chunk ch (2 kc-steps) from xt[ch&1]
#pragma unroll
        for (int kl = 0; kl < 2; ++kl) {
            const int kc = ch * 2 + kl;
            const float* srcl = &xt[ch & 1][(kl * 32 + quad * 8) * RS + wcol];
            float va[8];
#pragma unroll
            for (int j = 0; j < 8; ++j) va[j] = srcl[j * RS];
            short8 a;
#pragma unroll
            for (int j = 0; j < 8; ++j) { xsqp += va[j] * va[j]; a[j] = (short)f2bf(va[j]); }
            const int cb = kc * 32 + quad * 8;
            const short8 b0 = pack8(*(const float4*)&cw[col * CC + cb],
                                    *(const float4*)&cw[col * CC + cb + 4]);
            const short8 b1 = pack8(*(const float4*)&cw[(col + 16) * CC + cb],
                                    *(const float4*)&cw[(col + 16) * CC + cb + 4]);
            acc0 = __builtin_amdgcn_mfma_f32_16x16x32_bf16(a, b0, acc0, 0, 0, 0);
            acc1 = __builtin_amdgcn_mfma_f32_16x16x32_bf16(a, b1, acc1, 0, 0, 0);
        }
        asm volatile("s_waitcnt lgkmcnt(0)" ::: "memory");
        __builtin_amdgcn_s_barrier();
        asm volatile("" ::: "memory");
    }

    // xsq: sum quad slices -> every lane has xsq for its col's px
    xsqp += __shfl_xor(xsqp, 16);
    xsqp += __shfl_xor(xsqp, 32);

    const float s0 = scale[col], s1 = scale[col + 16];
    const float q0 = csq_l[col], q1 = csq_l[col + 16];

    // fused softmax epilogue; D row = px = quad*4+r, col = k
    unsigned short* Ab = Ag + (size_t)b * KK * AS + p0 + w * 16;
    float ts0 = 0.f, ts1 = 0.f;   // per-lane partial wsum over this tile
#pragma unroll
    for (int r = 0; r < 4; ++r) {
        const float xq = __shfl(xsqp, quad * 4 + r);   // lane (quad*4+r) holds that px's xsq
        const float d0 = s0 * (xq + q0 - 2.f * acc0[r]);
        const float d1 = s1 * (xq + q1 - 2.f * acc1[r]);
        float mx = fmaxf(d0, d1);
        mx = fmaxf(mx, __shfl_xor(mx, 1));
        mx = fmaxf(mx, __shfl_xor(mx, 2));
        mx = fmaxf(mx, __shfl_xor(mx, 4));
        mx = fmaxf(mx, __shfl_xor(mx, 8));
        const float e0 = __expf(d0 - mx), e1 = __expf(d1 - mx);
        float sm = e0 + e1;
        sm += __shfl_xor(sm, 1);
        sm += __shfl_xor(sm, 2);
        sm += __shfl_xor(sm, 4);
        sm += __shfl_xor(sm, 8);
        const float inv = 1.f / sm;
        const float a0 = e0 * inv, a1 = e1 * inv;
        Ab[col * AS + quad * 4 + r]        = f2bf(a0);
        Ab[(col + 16) * AS + quad * 4 + r] = f2bf(a1);
        ts0 += a0; ts1 += a1;
    }

    // per-tile wsum: reduce over the 4 quads (16 px of this tile)
    ts0 += __shfl_xor(ts0, 16); ts0 += __shfl_xor(ts0, 32);
    ts1 += __shfl_xor(ts1, 16); ts1 += __shfl_xor(ts1, 32);
    if (quad == 0) { wredA[w][col] = ts0; wredA[w][col + 16] = ts1; }
    __syncthreads();
    if (t < KK) {
        // split 12: tiles w=0..2 duplicate split 11's coverage -> count only w=3
        float s;
        if (split < 12) s = wredA[0][t] + wredA[1][t] + wredA[2][t] + wredA[3][t];
        else            s = wredA[3][t];
        float* wsf = (float*)(Ag + WSUM_OFF);
        wsf[(size_t)(split * BB + b) * KK + t] = s;
    }
}

// ---------------------------------------------------------------------------
// kB: per (c-chunk of 64, batch): out[k][c] = sum_n A[k][n] x[c][n] - wsum_k cw[k][c]
//  - barrier-free main loop, A (L2-hot) and x (L3-hot from kA) direct from global
//  - wsum from kA's per-split partials (13 adds per k)
// ---------------------------------------------------------------------------
__global__ __launch_bounds__(256) void kB(const float* __restrict__ x,
                                          const float* __restrict__ cw,
                                          const unsigned short* __restrict__ Ag,
                                          float* __restrict__ out)
{
    __shared__ float wsum_l[KK];

    const int t    = threadIdx.x;
    const int lane = t & 63, w = t >> 6;
    const int col  = lane & 15, quad = lane >> 4;
    const int cch  = blockIdx.x, b = blockIdx.y;

    const unsigned short* Ab = Ag + (size_t)b * KK * AS;

    // ---- wsum: sum kA's 13 per-split partials ----
    if (t < KK) {
        const float* wsf = (const float*)(Ag + WSUM_OFF);
        float s = 0.f;
#pragma unroll
        for (int sp = 0; sp < NSA; ++sp) s += wsf[(size_t)(sp * BB + b) * KK + t];
        wsum_l[t] = s;
    }

    // ---- main GEMM: this wave owns 16 c-rows; contract n = 0..800 ----
    const int c = cch * 64 + w * 16 + col;
    const float* xp = x + ((size_t)b * CC + c) * NPIX;
    const unsigned short* a0p = Ab + (size_t)col * AS;
    const unsigned short* a1p = Ab + (size_t)(col + 16) * AS;
    const int qo = quad * 8;

    floatx4 acc0 = {0.f, 0.f, 0.f, 0.f};
    floatx4 acc1 = {0.f, 0.f, 0.f, 0.f};
#pragma unroll 6
    for (int s = 0; s < NSTEP; ++s) {
        const int off = s * 32 + qo;
        const short8 av0 = *(const short8*)&a0p[off];
        const short8 av1 = *(const short8*)&a1p[off];
        const float4 xv0 = *(const float4*)&xp[off];
        const float4 xv1 = *(const float4*)&xp[off + 4];
        const short8 bv = pack8(xv0, xv1);
        acc0 = __builtin_amdgcn_mfma_f32_16x16x32_bf16(av0, bv, acc0, 0, 0, 0);
        acc1 = __builtin_amdgcn_mfma_f32_16x16x32_bf16(av1, bv, acc1, 0, 0, 0);
    }
    {   // tail step: n in [768,800); x rows end at 784 -> predicate quads 2,3 (A pad is zero)
        const int off = NSTEP * 32 + qo;
        const short8 av0 = *(const short8*)&a0p[off];
        const short8 av1 = *(const short8*)&a1p[off];
        float4 xv0 = make_float4(0.f, 0.f, 0.f, 0.f);
        float4 xv1 = make_float4(0.f, 0.f, 0.f, 0.f);
        if (quad < 2) {
            xv0 = *(const float4*)&xp[off];
            xv1 = *(const float4*)&xp[off + 4];
        }
        const short8 bv = pack8(xv0, xv1);
        acc0 = __builtin_amdgcn_mfma_f32_16x16x32_bf16(av0, bv, acc0, 0, 0, 0);
        acc1 = __builtin_amdgcn_mfma_f32_16x16x32_bf16(av1, bv, acc1, 0, 0, 0);
    }

    __syncthreads();   // wsum_l ready

    // ---- fused epilogue: out = W - wsum*cw ----
    float* ob = out + (size_t)b * KK * CC + c;
    const float* cp = cw + c;
#pragma unroll
    for (int r = 0; r < 4; ++r) {
        const int k0 = quad * 4 + r;
        ob[(size_t)k0 * CC]        = acc0[r] - wsum_l[k0]      * cp[(size_t)k0 * CC];
        ob[(size_t)(k0 + 16) * CC] = acc1[r] - wsum_l[k0 + 16] * cp[(size_t)(k0 + 16) * CC];
    }
}

extern "C" void kernel_launch(void* const* d_in, const int* in_sizes, int n_in,
                              void* d_out, int out_size, void* d_ws, size_t ws_size,
                              hipStream_t stream) {
    const float* x     = (const float*)d_in[0];   // (64, 512, 28, 28)
    const float* cw    = (const float*)d_in[1];   // (32, 512)
    const float* scale = (const float*)d_in[2];   // (32,)
    float* out = (float*)d_out;                   // (64, 32, 512)
    unsigned short* Ag = (unsigned short*)d_ws;   // A bf16 [64][32][800] + wsum_p f32 [13][64][32]

    kA<<<dim3(NSA, BB), dim3(256), 0, stream>>>(x, cw, scale, Ag);
    kB<<<dim3(8, BB), dim3(256), 0, stream>>>(x, cw, Ag, out);
}

// Round 8
// 182.210 us; speedup vs baseline: 1.0790x; 1.0790x over previous
//
#include <hip/hip_runtime.h>

#define BB 64
#define CC 512
#define NPIX 784
#define KK 32
#define NSA 13          // kA: 13 splits of 64 px (split 12 overlaps: p0=720)
#define AS 800          // A row stride in shorts (784 padded to 25*32)
#define CW_S 520        // cw LDS row stride (shorts): 260 dw == 4 mod 32 -> conflict-free b128
#define NSTEP 24        // kB full 32-wide n-steps (24*32 = 768), +1 predicated tail

typedef __attribute__((ext_vector_type(8))) short short8;
typedef __attribute__((ext_vector_type(4))) float floatx4;
typedef __attribute__((ext_vector_type(4))) unsigned short ushort4v;

// workspace layout: A bf16 [64][32][800] (3.28 MB), then wsum_p fp32 [13][64][32]
#define WSUM_OFF (BB * KK * AS)   // in shorts; byte offset 6553600 (16-aligned)

__device__ __forceinline__ unsigned short f2bf(float f) {
    union { float f; unsigned u; } v; v.f = f;
    return (unsigned short)((v.u + 0x7FFFu + ((v.u >> 16) & 1u)) >> 16);
}
__device__ __forceinline__ float bf2f(unsigned short h) {
    union { unsigned u; float f; } v; v.u = ((unsigned)h) << 16; return v.f;
}
__device__ __forceinline__ short8 pack8(const float4& a, const float4& b) {
    short8 r;
    r[0] = (short)f2bf(a.x); r[1] = (short)f2bf(a.y);
    r[2] = (short)f2bf(a.z); r[3] = (short)f2bf(a.w);
    r[4] = (short)f2bf(b.x); r[5] = (short)f2bf(b.y);
    r[6] = (short)f2bf(b.z); r[7] = (short)f2bf(b.w);
    return r;
}

// async gather: per-lane strided global src -> linear per-wave LDS dest (lane*4)
#define GLOAD_LDS(gp, lp)                                                       \
    __builtin_amdgcn_global_load_lds(                                           \
        (const __attribute__((address_space(1))) unsigned int*)(const void*)(gp), \
        (__attribute__((address_space(3))) unsigned int*)(void*)(lp), 4, 0, 0)

// issue one group (2 kc-steps = channels [g*64, g*64+64)) into gbuf[w][bf]
#define ISSUEG(g, bf) {                                                         \
    _Pragma("unroll")                                                           \
    for (int _kl = 0; _kl < 2; ++_kl) {                                         \
        _Pragma("unroll")                                                       \
        for (int _j = 0; _j < 8; ++_j) {                                        \
            const float* _src = xb + (size_t)((g) * 64 + _kl * 32 + quad * 8 + _j) * NPIX; \
            GLOAD_LDS(_src, &gbuf[w][bf][(_kl * 8 + _j) * 64]);                 \
        }                                                                       \
    } }

// ---------------------------------------------------------------------------
// kA: per (64-px split, batch): A[k][px] = softmax_k(scale_k*(xsq+csq_k-2 x.c_k))
//  - one 16-px MFMA tile per wave, FULL C=512 contraction per wave.
//  - the strided x gather goes through global_load_lds: per-lane strided
//    source, linear per-WAVE-PRIVATE LDS dest. No VGPR dest -> issue depth
//    not register-limited; counted s_waitcnt vmcnt(16) (never 0), and NO
//    barriers in the main loop (each wave owns its gather slab).
//    16-32 loads (4-8 KB) in flight per wave >> the ~8-load compiler window
//    that capped all register variants at ~2.4 TB/s.
//  - cw staged once to LDS bf16 (cs); fragments via conflict-free b128.
//  - A written bf16 to ws [b][k][n]; per-split wsum partials also written.
// ---------------------------------------------------------------------------
__global__ __launch_bounds__(256, 2) void kA(const float* __restrict__ x,
                                             const float* __restrict__ cw,
                                             const float* __restrict__ scale,
                                             unsigned short* __restrict__ Ag)
{
    __shared__ __align__(16) unsigned short cs[KK * CW_S];   // 33280 B
    __shared__ __align__(16) float gbuf[4][2][1024];         // 32768 B: per-wave dbuf gather
    __shared__ float csq_p[8][KK];
    __shared__ float csq_l[KK];
    __shared__ float wredA[4][KK];

    const int t    = threadIdx.x;
    const int lane = t & 63, w = t >> 6;
    const int col  = lane & 15, quad = lane >> 4;
    const int split = blockIdx.x, b = blockIdx.y;
    const int p0    = (split < 12) ? split * 64 : 720;   // split 12 overlaps by 48 px

    // ---- zero A pad region n in [784,800) once per batch (idempotent) ----
    if (split == 0 && t < 64) {
        const short8 z = {0, 0, 0, 0, 0, 0, 0, 0};
        const int k = t >> 1, off = (t & 1) * 8;
        *(short8*)&Ag[(size_t)b * KK * AS + (size_t)k * AS + NPIX + off] = z;
    }

    // ---- stage cw -> bf16 LDS ----
#pragma unroll 4
    for (int j = 0; j < 16; ++j) {
        const int qidx = t + j * 256;
        const int row = qidx >> 7, qc = qidx & 127;
        const float4 v = *(const float4*)&cw[row * CC + qc * 4];
        ushort4v p; p.x = f2bf(v.x); p.y = f2bf(v.y); p.z = f2bf(v.z); p.w = f2bf(v.w);
        *(ushort4v*)&cs[row * CW_S + qc * 4] = p;
    }
    __syncthreads();
    // ---- csq ----
    {
        const int k = t & 31, part = t >> 5;
        float s = 0.f;
        for (int i = 0; i < 64; ++i) {
            const float v = bf2f(cs[k * CW_S + part * 64 + i]);
            s += v * v;
        }
        csq_p[part][k] = s;
    }
    __syncthreads();
    if (t < KK) {
        float s = 0.f;
#pragma unroll
        for (int p = 0; p < 8; ++p) s += csq_p[p][t];
        csq_l[t] = s;
    }
    __syncthreads();   // drains vmcnt to 0: clean baseline for counted waits

    const float s0 = scale[col], s1 = scale[col + 16];
    const float q0 = csq_l[col], q1 = csq_l[col + 16];

    // ---- main MFMA: wave w owns px-tile [p0 + w*16, +16), contracts all C ----
    const int px = p0 + w * 16 + col;
    const float* xb = x + (size_t)b * CC * NPIX + px;

    floatx4 acc0 = {0.f, 0.f, 0.f, 0.f};
    floatx4 acc1 = {0.f, 0.f, 0.f, 0.f};
    float xsqp = 0.f;

    ISSUEG(0, 0);
#pragma unroll
    for (int g = 0; g < 8; ++g) {
        if (g < 7) {
            ISSUEG(g + 1, (g + 1) & 1);
            asm volatile("s_waitcnt vmcnt(16)" ::: "memory");   // group g done; g+1 in flight
        } else {
            asm volatile("s_waitcnt vmcnt(0)" ::: "memory");
        }
        __builtin_amdgcn_sched_barrier(0);
        // compute group g (2 kc-steps) from per-wave private gbuf[w][g&1]
#pragma unroll
        for (int kl = 0; kl < 2; ++kl) {
            const int kc = g * 2 + kl;
            float va[8];
#pragma unroll
            for (int j = 0; j < 8; ++j) va[j] = gbuf[w][g & 1][(kl * 8 + j) * 64 + lane];
            short8 a;
#pragma unroll
            for (int j = 0; j < 8; ++j) { xsqp += va[j] * va[j]; a[j] = (short)f2bf(va[j]); }
            const int cb = kc * 32 + quad * 8;
            const short8 b0 = *(const short8*)&cs[col * CW_S + cb];
            const short8 b1 = *(const short8*)&cs[(col + 16) * CW_S + cb];
            acc0 = __builtin_amdgcn_mfma_f32_16x16x32_bf16(a, b0, acc0, 0, 0, 0);
            acc1 = __builtin_amdgcn_mfma_f32_16x16x32_bf16(a, b1, acc1, 0, 0, 0);
        }
    }

    // xsq: sum quad slices -> every lane has xsq for its col's px
    xsqp += __shfl_xor(xsqp, 16);
    xsqp += __shfl_xor(xsqp, 32);

    // fused softmax epilogue; D row = px = quad*4+r, col = k
    unsigned short* Ab = Ag + (size_t)b * KK * AS + p0 + w * 16;
    float ts0 = 0.f, ts1 = 0.f;   // per-lane partial wsum over this tile
#pragma unroll
    for (int r = 0; r < 4; ++r) {
        const float xq = __shfl(xsqp, quad * 4 + r);   // lane (quad*4+r) holds that px's xsq
        const float d0 = s0 * (xq + q0 - 2.f * acc0[r]);
        const float d1 = s1 * (xq + q1 - 2.f * acc1[r]);
        float mx = fmaxf(d0, d1);
        mx = fmaxf(mx, __shfl_xor(mx, 1));
        mx = fmaxf(mx, __shfl_xor(mx, 2));
        mx = fmaxf(mx, __shfl_xor(mx, 4));
        mx = fmaxf(mx, __shfl_xor(mx, 8));
        const float e0 = __expf(d0 - mx), e1 = __expf(d1 - mx);
        float sm = e0 + e1;
        sm += __shfl_xor(sm, 1);
        sm += __shfl_xor(sm, 2);
        sm += __shfl_xor(sm, 4);
        sm += __shfl_xor(sm, 8);
        const float inv = 1.f / sm;
        const float a0 = e0 * inv, a1 = e1 * inv;
        Ab[col * AS + quad * 4 + r]        = f2bf(a0);
        Ab[(col + 16) * AS + quad * 4 + r] = f2bf(a1);
        ts0 += a0; ts1 += a1;
    }

    // per-tile wsum: reduce over the 4 quads (16 px of this tile)
    ts0 += __shfl_xor(ts0, 16); ts0 += __shfl_xor(ts0, 32);
    ts1 += __shfl_xor(ts1, 16); ts1 += __shfl_xor(ts1, 32);
    if (quad == 0) { wredA[w][col] = ts0; wredA[w][col + 16] = ts1; }
    __syncthreads();
    if (t < KK) {
        // split 12: tiles w=0..2 duplicate split 11's coverage -> count only w=3
        float s;
        if (split < 12) s = wredA[0][t] + wredA[1][t] + wredA[2][t] + wredA[3][t];
        else            s = wredA[3][t];
        float* wsf = (float*)(Ag + WSUM_OFF);
        wsf[(size_t)(split * BB + b) * KK + t] = s;
    }
}

// ---------------------------------------------------------------------------
// kB: per (c-chunk of 64, batch): out[k][c] = sum_n A[k][n] x[c][n] - wsum_k cw[k][c]
//  - barrier-free main loop, A (L2-hot) and x (L3-hot from kA) direct from global
//  - wsum from kA's per-split partials (13 adds per k)
// ---------------------------------------------------------------------------
__global__ __launch_bounds__(256) void kB(const float* __restrict__ x,
                                          const float* __restrict__ cw,
                                          const unsigned short* __restrict__ Ag,
                                          float* __restrict__ out)
{
    __shared__ float wsum_l[KK];

    const int t    = threadIdx.x;
    const int lane = t & 63, w = t >> 6;
    const int col  = lane & 15, quad = lane >> 4;
    const int cch  = blockIdx.x, b = blockIdx.y;

    const unsigned short* Ab = Ag + (size_t)b * KK * AS;

    // ---- wsum: sum kA's 13 per-split partials ----
    if (t < KK) {
        const float* wsf = (const float*)(Ag + WSUM_OFF);
        float s = 0.f;
#pragma unroll
        for (int sp = 0; sp < NSA; ++sp) s += wsf[(size_t)(sp * BB + b) * KK + t];
        wsum_l[t] = s;
    }

    // ---- main GEMM: this wave owns 16 c-rows; contract n = 0..800 ----
    const int c = cch * 64 + w * 16 + col;
    const float* xp = x + ((size_t)b * CC + c) * NPIX;
    const unsigned short* a0p = Ab + (size_t)col * AS;
    const unsigned short* a1p = Ab + (size_t)(col + 16) * AS;
    const int qo = quad * 8;

    floatx4 acc0 = {0.f, 0.f, 0.f, 0.f};
    floatx4 acc1 = {0.f, 0.f, 0.f, 0.f};
#pragma unroll 6
    for (int s = 0; s < NSTEP; ++s) {
        const int off = s * 32 + qo;
        const short8 av0 = *(const short8*)&a0p[off];
        const short8 av1 = *(const short8*)&a1p[off];
        const float4 xv0 = *(const float4*)&xp[off];
        const float4 xv1 = *(const float4*)&xp[off + 4];
        const short8 bv = pack8(xv0, xv1);
        acc0 = __builtin_amdgcn_mfma_f32_16x16x32_bf16(av0, bv, acc0, 0, 0, 0);
        acc1 = __builtin_amdgcn_mfma_f32_16x16x32_bf16(av1, bv, acc1, 0, 0, 0);
    }
    {   // tail step: n in [768,800); x rows end at 784 -> predicate quads 2,3 (A pad is zero)
        const int off = NSTEP * 32 + qo;
        const short8 av0 = *(const short8*)&a0p[off];
        const short8 av1 = *(const short8*)&a1p[off];
        float4 xv0 = make_float4(0.f, 0.f, 0.f, 0.f);
        float4 xv1 = make_float4(0.f, 0.f, 0.f, 0.f);
        if (quad < 2) {
            xv0 = *(const float4*)&xp[off];
            xv1 = *(const float4*)&xp[off + 4];
        }
        const short8 bv = pack8(xv0, xv1);
        acc0 = __builtin_amdgcn_mfma_f32_16x16x32_bf16(av0, bv, acc0, 0, 0, 0);
        acc1 = __builtin_amdgcn_mfma_f32_16x16x32_bf16(av1, bv, acc1, 0, 0, 0);
    }

    __syncthreads();   // wsum_l ready

    // ---- fused epilogue: out = W - wsum*cw ----
    float* ob = out + (size_t)b * KK * CC + c;
    const float* cp = cw + c;
#pragma unroll
    for (int r = 0; r < 4; ++r) {
        const int k0 = quad * 4 + r;
        ob[(size_t)k0 * CC]        = acc0[r] - wsum_l[k0]      * cp[(size_t)k0 * CC];
        ob[(size_t)(k0 + 16) * CC] = acc1[r] - wsum_l[k0 + 16] * cp[(size_t)(k0 + 16) * CC];
    }
}

extern "C" void kernel_launch(void* const* d_in, const int* in_sizes, int n_in,
                              void* d_out, int out_size, void* d_ws, size_t ws_size,
                              hipStream_t stream) {
    const float* x     = (const float*)d_in[0];   // (64, 512, 28, 28)
    const float* cw    = (const float*)d_in[1];   // (32, 512)
    const float* scale = (const float*)d_in[2];   // (32,)
    float* out = (float*)d_out;                   // (64, 32, 512)
    unsigned short* Ag = (unsigned short*)d_ws;   // A bf16 [64][32][800] + wsum_p f32 [13][64][32]

    kA<<<dim3(NSA, BB), dim3(256), 0, stream>>>(x, cw, scale, Ag);
    kB<<<dim3(8, BB), dim3(256), 0, stream>>>(x, cw, Ag, out);
}